// Round 10
// baseline (588.908 us; speedup 1.0000x reference)
//
#include <hip/hip_runtime.h>
#include <math.h>

// Problem constants
#define BB 64
#define LL 24
#define DD 512
#define GG 2560        // 5*H
#define NSTEP 23       // LL-1
#define NTILES 160     // stepB n-tiles: 5120/32

// Cache layout (round-8-verified pair-major): a/b cache column for (gate g,
// dim d) is col(d,g) = (d/2)*10 + g*2 + (d%2): one dim-pair's 5 gates are 40
// contiguous bytes. splitW_k permutes W rows; GEMMs are layout-agnostic.

__device__ __forceinline__ float sigm(float x) { return 1.0f / (1.0f + __expf(-x)); }

// bf16 split helpers (RNE)
__device__ __forceinline__ unsigned short f2bf(float x) {
    unsigned u = __float_as_uint(x);
    unsigned r = (u + 0x7fff + ((u >> 16) & 1)) >> 16;
    return (unsigned short)r;
}
__device__ __forceinline__ float bf2f(unsigned short b) {
    return __uint_as_float(((unsigned)b) << 16);
}

using short8 = __attribute__((ext_vector_type(8))) short;
using f32x4 = __attribute__((ext_vector_type(4))) float;

// gate math for one dim pair (round-8 verified)
__device__ __forceinline__ void gatepair(const float* ar, const float* br,
                                         const float* cb,
                                         float cl0, float cl1, float cr0, float cr1,
                                         float nh[2], float nc[2]) {
    float2 A0 = *(const float2*)(ar + 0), B0 = *(const float2*)(br + 0), C0 = *(const float2*)(cb + 0);
    float2 A1 = *(const float2*)(ar + 2), B1 = *(const float2*)(br + 2), C1 = *(const float2*)(cb + 2);
    float2 A2 = *(const float2*)(ar + 4), B2 = *(const float2*)(br + 4), C2 = *(const float2*)(cb + 4);
    float2 A3 = *(const float2*)(ar + 6), B3 = *(const float2*)(br + 6), C3 = *(const float2*)(cb + 6);
    float2 A4 = *(const float2*)(ar + 8), B4 = *(const float2*)(br + 8), C4 = *(const float2*)(cb + 8);
    float gi0 = A0.x + B0.x + C0.x, gi1 = A0.y + B0.y + C0.y;
    float gfl0 = A1.x + B1.x + C1.x, gfl1 = A1.y + B1.y + C1.y;
    float gfr0 = A2.x + B2.x + C2.x, gfr1 = A2.y + B2.y + C2.y;
    float gu0 = A3.x + B3.x + C3.x, gu1 = A3.y + B3.y + C3.y;
    float go0 = A4.x + B4.x + C4.x, go1 = A4.y + B4.y + C4.y;
    nc[0] = cl0 * sigm(gfl0 + 1.f) + cr0 * sigm(gfr0 + 1.f) + tanhf(gu0) * sigm(gi0);
    nc[1] = cl1 * sigm(gfl1 + 1.f) + cr1 * sigm(gfr1 + 1.f) + tanhf(gu1) * sigm(gi1);
    nh[0] = sigm(go0) * tanhf(nc[0]);
    nh[1] = sigm(go1) * tanhf(nc[1]);
}

// ---------------------------------------------------------------------------
// one-time: split comp_W into bf16 hi/lo, PERMUTED rows [5120][512]
// ---------------------------------------------------------------------------
__global__ __launch_bounds__(256) void splitW_k(const float* __restrict__ comp_W,
                                                unsigned short* __restrict__ Wh,
                                                unsigned short* __restrict__ Wl) {
    int t = (blockIdx.x * 256 + threadIdx.x) * 4;
    int n = t >> 9;
    int k = t & 511;
    int p = (n >= GG) ? 1 : 0;
    int r = n - p * GG;
    int g = (r % 10) >> 1;
    int d = (r / 10) * 2 + (r & 1);
    const float* src = comp_W + (size_t)(g * 512 + d) * (2 * DD) + p * DD + k;
    float4 v = *(const float4*)src;
    ushort4 h, l;
    h.x = f2bf(v.x); l.x = f2bf(v.x - bf2f(h.x));
    h.y = f2bf(v.y); l.y = f2bf(v.y - bf2f(h.y));
    h.z = f2bf(v.z); l.z = f2bf(v.z - bf2f(h.z));
    h.w = f2bf(v.w); l.w = f2bf(v.w - bf2f(h.w));
    *(ushort4*)(Wh + t) = h;
    *(ushort4*)(Wl + t) = l;
}

// permuted comp_b: cbp[col(d,g)] = comp_b[g*512+d]
__global__ __launch_bounds__(256) void compbp_k(const float* __restrict__ comp_b,
                                                float* __restrict__ cbp) {
    int c = blockIdx.x * 256 + threadIdx.x;   // 2560
    int g = (c % 10) >> 1;
    int d = (c / 10) * 2 + (c & 1);
    cbp[c] = comp_b[g * 512 + d];
}

// ---------------------------------------------------------------------------
// generic flat bf16 hi/lo split (layout-preserving)
// ---------------------------------------------------------------------------
__global__ __launch_bounds__(256) void splitF_k(const float* __restrict__ src,
                                                unsigned short* __restrict__ dh,
                                                unsigned short* __restrict__ dl) {
    int t = (blockIdx.x * 256 + threadIdx.x) * 4;
    float4 v = *(const float4*)(src + t);
    ushort4 h, l;
    h.x = f2bf(v.x); l.x = f2bf(v.x - bf2f(h.x));
    h.y = f2bf(v.y); l.y = f2bf(v.y - bf2f(h.y));
    h.z = f2bf(v.z); l.z = f2bf(v.z - bf2f(h.z));
    h.w = f2bf(v.w); l.w = f2bf(v.w - bf2f(h.w));
    *(ushort4*)(dh + t) = h;
    *(ushort4*)(dl + t) = l;
}

// ---------------------------------------------------------------------------
// gemm64w_mfma: word projection via bf16x3 MFMA (round-7 verified, unchanged)
// ---------------------------------------------------------------------------
__global__ __launch_bounds__(256) void gemm64w_mfma(
    const unsigned short* __restrict__ Ih, const unsigned short* __restrict__ Il,
    const unsigned short* __restrict__ Vh, const unsigned short* __restrict__ Vl,
    const float* __restrict__ bias,
    unsigned short* __restrict__ Ah, unsigned short* __restrict__ Al,
    float* __restrict__ O1) {
    __shared__ unsigned short AhS[64][72];
    __shared__ unsigned short AlS[64][72];
    __shared__ unsigned short BhS[128][72];
    __shared__ unsigned short BlS[128][72];

    const int tid = threadIdx.x;
    const int m0 = (blockIdx.x % 24) * 64;
    const int n0 = (blockIdx.x / 24) * 128;

    const int w = tid >> 6, lane = tid & 63;
    const int mq = w >> 1, nq = w & 1;
    const int lr = lane & 15, kg = lane >> 4;

    const int srow = tid >> 3;
    const int sk8 = tid & 7;

    const unsigned short* agh = Ih + (size_t)(m0 + srow) * DD + sk8 * 8;
    const unsigned short* agl = Il + (size_t)(m0 + srow) * DD + sk8 * 8;
    const unsigned short* bgh = Vh + (size_t)(n0 + srow) * DD + sk8 * 8;
    const unsigned short* bgl = Vl + (size_t)(n0 + srow) * DD + sk8 * 8;

    f32x4 acc[2][4];
#pragma unroll
    for (int mt = 0; mt < 2; ++mt)
#pragma unroll
        for (int nt = 0; nt < 4; ++nt) acc[mt][nt] = (f32x4){0.f, 0.f, 0.f, 0.f};

    short8 rAh[2], rAl[2], rBh[4], rBl[4];

#define LOADT(kt)                                                            \
    {                                                                        \
        _Pragma("unroll")                                                    \
        for (int it = 0; it < 2; ++it) {                                     \
            const size_t ro = (size_t)it * 32 * DD + (kt);                   \
            rAh[it] = *(const short8*)(agh + ro);                            \
            rAl[it] = *(const short8*)(agl + ro);                            \
        }                                                                    \
        _Pragma("unroll")                                                    \
        for (int it = 0; it < 4; ++it) {                                     \
            const size_t ro = (size_t)it * 32 * DD + (kt);                   \
            rBh[it] = *(const short8*)(bgh + ro);                            \
            rBl[it] = *(const short8*)(bgl + ro);                            \
        }                                                                    \
    }
#define WRITET()                                                             \
    {                                                                        \
        _Pragma("unroll")                                                    \
        for (int it = 0; it < 2; ++it) {                                     \
            const int row = srow + it * 32;                                  \
            *(short8*)&AhS[row][sk8 * 8] = rAh[it];                          \
            *(short8*)&AlS[row][sk8 * 8] = rAl[it];                          \
        }                                                                    \
        _Pragma("unroll")                                                    \
        for (int it = 0; it < 4; ++it) {                                     \
            const int row = srow + it * 32;                                  \
            *(short8*)&BhS[row][sk8 * 8] = rBh[it];                          \
            *(short8*)&BlS[row][sk8 * 8] = rBl[it];                          \
        }                                                                    \
    }

    LOADT(0);
    WRITET();
    __syncthreads();

    for (int kti = 0; kti < 8; ++kti) {
        if (kti + 1 < 8) LOADT((kti + 1) * 64);
#pragma unroll
        for (int ks2 = 0; ks2 < 2; ++ks2) {
            const int kb = ks2 * 32 + kg * 8;
            short8 fah[2], fal[2], fbh[4], fbl[4];
#pragma unroll
            for (int t = 0; t < 2; ++t) {
                fah[t] = *(const short8*)&AhS[mq * 32 + t * 16 + lr][kb];
                fal[t] = *(const short8*)&AlS[mq * 32 + t * 16 + lr][kb];
            }
#pragma unroll
            for (int t = 0; t < 4; ++t) {
                fbh[t] = *(const short8*)&BhS[nq * 64 + t * 16 + lr][kb];
                fbl[t] = *(const short8*)&BlS[nq * 64 + t * 16 + lr][kb];
            }
#pragma unroll
            for (int mt = 0; mt < 2; ++mt)
#pragma unroll
                for (int nt = 0; nt < 4; ++nt) {
                    acc[mt][nt] = __builtin_amdgcn_mfma_f32_16x16x32_bf16(fal[mt], fbh[nt], acc[mt][nt], 0, 0, 0);
                    acc[mt][nt] = __builtin_amdgcn_mfma_f32_16x16x32_bf16(fah[mt], fbl[nt], acc[mt][nt], 0, 0, 0);
                    acc[mt][nt] = __builtin_amdgcn_mfma_f32_16x16x32_bf16(fah[mt], fbh[nt], acc[mt][nt], 0, 0, 0);
                }
        }
        __syncthreads();
        if (kti + 1 < 8) {
            WRITET();
            __syncthreads();
        }
    }
#undef LOADT
#undef WRITET

#pragma unroll
    for (int mt = 0; mt < 2; ++mt) {
        const int mbase = m0 + mq * 32 + mt * 16 + kg * 4;
#pragma unroll
        for (int nt = 0; nt < 4; ++nt) {
            const int n = n0 + nq * 64 + nt * 16 + lr;
            const float bv = bias[n];
#pragma unroll
            for (int r = 0; r < 4; ++r) {
                const int m = mbase + r;
                float v = acc[mt][nt][r] + bv;
                if (n < DD) {
                    unsigned short hv = f2bf(v);
                    Ah[(size_t)m * DD + n] = hv;
                    Al[(size_t)m * DD + n] = f2bf(v - bf2f(hv));
                } else {
                    O1[(size_t)m * DD + (n - DD)] = v;
                }
            }
        }
    }
}

// ---------------------------------------------------------------------------
// gemm_big_mfma v3: LDS-staged bf16x3 MFMA GEMM (round-6 verified, unchanged)
// ---------------------------------------------------------------------------
__global__ __launch_bounds__(256) void gemm_big_mfma(
    const unsigned short* __restrict__ Ah, const unsigned short* __restrict__ Al,
    const unsigned short* __restrict__ Wh, const unsigned short* __restrict__ Wl,
    float* __restrict__ O0, float* __restrict__ O1) {
    __shared__ unsigned short AhS[128][72];
    __shared__ unsigned short AlS[128][72];
    __shared__ unsigned short BhS[128][72];
    __shared__ unsigned short BlS[128][72];

    const int tid = threadIdx.x;
    const int xcd = blockIdx.x & 7, idx = blockIdx.x >> 3;
    const int n0 = (xcd * 5 + idx % 5) * 128;
    const int m0 = (idx / 5) * 128;

    const int w = tid >> 6, lane = tid & 63;
    const int mq = w >> 1, nq = w & 1;
    const int lr = lane & 15, kg = lane >> 4;

    const int srow = tid >> 3;
    const int sk8 = tid & 7;

    const unsigned short* agh = Ah + (size_t)(m0 + srow) * DD + sk8 * 8;
    const unsigned short* agl = Al + (size_t)(m0 + srow) * DD + sk8 * 8;
    const unsigned short* bgh = Wh + (size_t)(n0 + srow) * DD + sk8 * 8;
    const unsigned short* bgl = Wl + (size_t)(n0 + srow) * DD + sk8 * 8;

    f32x4 acc[4][4];
#pragma unroll
    for (int mt = 0; mt < 4; ++mt)
#pragma unroll
        for (int nt = 0; nt < 4; ++nt) acc[mt][nt] = (f32x4){0.f, 0.f, 0.f, 0.f};

    short8 rAh[4], rAl[4], rBh[4], rBl[4];

#define LOADT(kt)                                                            \
    {                                                                        \
        _Pragma("unroll")                                                    \
        for (int it = 0; it < 4; ++it) {                                     \
            const size_t ro = (size_t)it * 32 * DD + (kt);                   \
            rAh[it] = *(const short8*)(agh + ro);                            \
            rAl[it] = *(const short8*)(agl + ro);                            \
            rBh[it] = *(const short8*)(bgh + ro);                            \
            rBl[it] = *(const short8*)(bgl + ro);                            \
        }                                                                    \
    }
#define WRITET()                                                             \
    {                                                                        \
        _Pragma("unroll")                                                    \
        for (int it = 0; it < 4; ++it) {                                     \
            const int row = srow + it * 32;                                  \
            *(short8*)&AhS[row][sk8 * 8] = rAh[it];                          \
            *(short8*)&AlS[row][sk8 * 8] = rAl[it];                          \
            *(short8*)&BhS[row][sk8 * 8] = rBh[it];                          \
            *(short8*)&BlS[row][sk8 * 8] = rBl[it];                          \
        }                                                                    \
    }

    LOADT(0);
    WRITET();
    __syncthreads();

    for (int kti = 0; kti < 8; ++kti) {
        if (kti + 1 < 8) LOADT((kti + 1) * 64);
#pragma unroll
        for (int ks2 = 0; ks2 < 2; ++ks2) {
            const int kb = ks2 * 32 + kg * 8;
            short8 fah[4], fal[4], fbh[4], fbl[4];
#pragma unroll
            for (int t = 0; t < 4; ++t) {
                fah[t] = *(const short8*)&AhS[mq * 64 + t * 16 + lr][kb];
                fal[t] = *(const short8*)&AlS[mq * 64 + t * 16 + lr][kb];
                fbh[t] = *(const short8*)&BhS[nq * 64 + t * 16 + lr][kb];
                fbl[t] = *(const short8*)&BlS[nq * 64 + t * 16 + lr][kb];
            }
#pragma unroll
            for (int mt = 0; mt < 4; ++mt)
#pragma unroll
                for (int nt = 0; nt < 4; ++nt) {
                    acc[mt][nt] = __builtin_amdgcn_mfma_f32_16x16x32_bf16(fal[mt], fbh[nt], acc[mt][nt], 0, 0, 0);
                    acc[mt][nt] = __builtin_amdgcn_mfma_f32_16x16x32_bf16(fah[mt], fbl[nt], acc[mt][nt], 0, 0, 0);
                    acc[mt][nt] = __builtin_amdgcn_mfma_f32_16x16x32_bf16(fah[mt], fbh[nt], acc[mt][nt], 0, 0, 0);
                }
        }
        __syncthreads();
        if (kti + 1 < 8) {
            WRITET();
            __syncthreads();
        }
    }
#undef LOADT
#undef WRITET

#pragma unroll
    for (int mt = 0; mt < 4; ++mt) {
        const int mbase = m0 + mq * 64 + mt * 16 + kg * 4;
#pragma unroll
        for (int nt = 0; nt < 4; ++nt) {
            const int n = n0 + nq * 64 + nt * 16 + lr;
#pragma unroll
            for (int r = 0; r < 4; ++r) {
                const int m = mbase + r;
                float* dst = (n < GG) ? (O0 + (size_t)m * GG + n)
                                      : (O1 + (size_t)m * GG + (n - GG));
                *dst = acc[mt][nt][r];
            }
        }
    }
}

// ---------------------------------------------------------------------------
// half-block (128-lane) candidate scorer — pair layout (round-8 verified)
// ---------------------------------------------------------------------------
__device__ __forceinline__ float half_dot(const float* __restrict__ ar,
                                          const float* __restrict__ br,
                                          const float* __restrict__ cbp,
                                          const float* __restrict__ cl,
                                          const float* __restrict__ cr,
                                          const float* __restrict__ q, int lane) {
    float part = 0.f;
#pragma unroll
    for (int pr = lane; pr < 256; pr += 128) {
        const int base = pr * 10, d0 = pr * 2;
        float nh[2], nc[2];
        gatepair(ar + base, br + base, cbp + base,
                 cl[d0], cl[d0 + 1], cr[d0], cr[d0 + 1], nh, nc);
        float2 Q = *(const float2*)(q + d0);
        part += nh[0] * Q.x + nh[1] * Q.y;
    }
#pragma unroll
    for (int off = 32; off; off >>= 1) part += __shfl_down(part, off);
    return part;
}

// ---------------------------------------------------------------------------
// initial scores: grid (12, 64)
// ---------------------------------------------------------------------------
__global__ __launch_bounds__(256) void scoreall_k(const float* __restrict__ acache,
                                                  const float* __restrict__ bcache,
                                                  const float* __restrict__ cbuf,
                                                  const float* __restrict__ cbp,
                                                  const float* __restrict__ q,
                                                  float* __restrict__ scores_g) {
    __shared__ float red_s[4];
    const int tid = threadIdx.x;
    const int b = blockIdx.y;
    const int p = blockIdx.x * 2 + (tid >> 7);
    const bool valid = p < NSTEP;
    float w = 0.f;
    if (valid) {
        w = half_dot(acache + (size_t)(b * LL + p) * GG,
                     bcache + (size_t)(b * LL + p + 1) * GG, cbp,
                     cbuf + (size_t)(b * LL + p) * DD,
                     cbuf + (size_t)(b * LL + p + 1) * DD, q, tid & 127);
    }
    if ((tid & 63) == 0) red_s[tid >> 6] = w;
    __syncthreads();
    if ((tid == 0 || tid == 128) && valid) {
        int base = tid >> 6;
        scores_g[b * NSTEP + p] = red_s[base] + red_s[base + 1];
    }
}

// ---------------------------------------------------------------------------
// stepA (v3): rescore candidates come from rescPre (precomputed item-ids by
// the previous step) -> rescore loads issue at entry with no seq dependency.
// Wave-parallel argmax (first-max-index tie-break, identical to serial >).
// Merge + state shift + rescPre publication for the next step.
// ---------------------------------------------------------------------------
__global__ __launch_bounds__(256) void stepA_k(
    int i, const int* __restrict__ length, float* __restrict__ cbuf,
    const float* __restrict__ acache, const float* __restrict__ bcache,
    float* __restrict__ hout, unsigned short* __restrict__ hh,
    unsigned short* __restrict__ hl, float* __restrict__ scores_g,
    int* __restrict__ seq_g, int* __restrict__ kp_g, int4* __restrict__ rescPre,
    int* __restrict__ msel, const float* __restrict__ cbp,
    const float* __restrict__ q, float* __restrict__ out) {
    __shared__ float red_s[4];
    __shared__ float sc_l[32];
    __shared__ int seq_l[32];
    __shared__ int k_sh;
    const int tid = threadIdx.x;
    const int b = blockIdx.x;
    const int lenb = length[b];
    const int ncand = NSTEP - i;

    // rescore first: row ids come from rescPre (no seq dependency)
    if (i > 0) {
        const int4 rp = rescPre[b];           // {sL, sN, sN or -1, sR}
        const int sl = (tid < 128) ? rp.x : rp.z;
        const int sr = (tid < 128) ? rp.y : rp.w;
        float w = 0.f;
        if (sl >= 0) {
            w = half_dot(acache + (size_t)(b * LL + sl) * GG,
                         bcache + (size_t)(b * LL + sr) * GG, cbp,
                         cbuf + (size_t)(b * LL + sl) * DD,
                         cbuf + (size_t)(b * LL + sr) * DD, q, tid & 127);
        }
        if ((tid & 63) == 0) red_s[tid >> 6] = w;
    }

    // state staging (overlaps the rescore loads above)
    if (i == 0) {
        if (tid < LL) seq_l[tid] = tid;
    } else {
        if (tid < LL - i) seq_l[tid] = seq_g[b * 32 + tid];
    }
    if (tid < ncand) sc_l[tid] = scores_g[b * NSTEP + tid];
    __syncthreads();

    if (i > 0 && tid == 0) {
        const int4 rp = rescPre[b];
        const int kp = kp_g[b];
        if (rp.x >= 0) sc_l[kp - 1] = red_s[0] + red_s[1];
        if (rp.z >= 0) sc_l[kp] = red_s[2] + red_s[3];
    }
    __syncthreads();

    if (i + 1 < lenb) {
        // wave-parallel argmax over sc_l[0..vmax] (first-index tie-break)
        if (tid < 64) {
            const int vmax = lenb - i - 2;
            float v = (tid <= vmax) ? sc_l[tid] : -3.0e38f;
            int idx = tid;
#pragma unroll
            for (int off = 32; off; off >>= 1) {
                float v2 = __shfl_down(v, off);
                int i2 = __shfl_down(idx, off);
                if (v2 > v || (v2 == v && i2 < idx)) { v = v2; idx = i2; }
            }
            if (tid == 0) k_sh = idx;
        }
        __syncthreads();
        const int k = k_sh;
        const int sl = seq_l[k], sr = seq_l[k + 1];
        // capture next step's rescore pair item-ids PRE-shift
        int sLn = -1, sRn = -1;
        if (tid == 0) {
            if (k > 0) sLn = seq_l[k - 1];
            if (k < NSTEP - i - 1) sRn = seq_l[k + 2];
        }
        const float* ar = acache + (size_t)(b * LL + sl) * GG;
        const float* br = bcache + (size_t)(b * LL + sr) * GG;
        const float* cl = cbuf + (size_t)(b * LL + sl) * DD;
        const float* cr = cbuf + (size_t)(b * LL + sr) * DD;
        {
            const int d = 2 * tid, base = tid * 10;
            float nh[2], nc[2];
            gatepair(ar + base, br + base, cbp + base,
                     cl[d], cl[d + 1], cr[d], cr[d + 1], nh, nc);
            *(float2*)(cbuf + (size_t)(b * LL + sl) * DD + d) = make_float2(nc[0], nc[1]);
            *(float2*)(hout + (size_t)b * DD + d) = make_float2(nh[0], nh[1]);
            ushort2 hv, lv;
            hv.x = f2bf(nh[0]); lv.x = f2bf(nh[0] - bf2f(hv.x));
            hv.y = f2bf(nh[1]); lv.y = f2bf(nh[1] - bf2f(hv.y));
            *(ushort2*)(hh + (size_t)b * DD + d) = hv;
            *(ushort2*)(hl + (size_t)b * DD + d) = lv;
            if (i == NSTEP - 1)
                *(float2*)(out + (size_t)b * DD + d) = make_float2(nh[0], nh[1]);
        }
        float sv = (tid + 1 < ncand) ? sc_l[tid + 1] : 0.f;
        int qv = (tid + 1 < LL - i) ? seq_l[tid + 1] : 0;
        __syncthreads();
        if (tid >= k + 1 && tid <= ncand - 2) sc_l[tid] = sv;
        if (tid >= k + 1 && tid <= LL - i - 2) seq_l[tid] = qv;
        if (tid < ncand - 1) scores_g[b * NSTEP + tid] = sc_l[tid];
        if (tid < LL - i - 1) seq_g[b * 32 + tid] = seq_l[tid];
        if (tid == 0) {
            kp_g[b] = k;
            msel[b] = sl;
            rescPre[b] = make_int4(sLn, sl, (sRn >= 0) ? sl : -1, sRn);
        }
    } else {
        if (tid == 0) rescPre[b] = make_int4(-1, 0, -1, 0);
        if (i == NSTEP - 1) {
            const int d = 2 * tid;
            *(float2*)(out + (size_t)b * DD + d) = *(const float2*)(hout + (size_t)b * DD + d);
        }
    }
}

// ---------------------------------------------------------------------------
// stepB (v3): no LDS / no entry barrier — each thread loads msel for its own
// 8 output rows into registers at entry (L2-broadcast), consumed only in the
// epilogue scatter. GEMM identical to the round-7-verified version.
// ---------------------------------------------------------------------------
__global__ __launch_bounds__(256) void stepB_mfma(
    const unsigned short* __restrict__ hh, const unsigned short* __restrict__ hl,
    const int* __restrict__ msel,
    const unsigned short* __restrict__ Wh, const unsigned short* __restrict__ Wl,
    float* __restrict__ acache, float* __restrict__ bcache) {
    const int tid = threadIdx.x;
    const int bid = blockIdx.x;
    const int w = tid >> 6, lane = tid & 63;
    const int mt0 = (w >> 1) * 2;
    const int nt = w & 1;
    const int lr = lane & 15;
    const int kg = lane >> 4;
    const int n = bid * 32 + nt * 16 + lr;

    // early per-thread msel loads (independent of the GEMM; used at the end)
    int ms0[4], ms1[4];
#pragma unroll
    for (int r = 0; r < 4; ++r) {
        ms0[r] = msel[mt0 * 16 + kg * 4 + r];
        ms1[r] = msel[(mt0 + 1) * 16 + kg * 4 + r];
    }

    const unsigned short* wh_row = Wh + (size_t)n * DD;
    const unsigned short* wl_row = Wl + (size_t)n * DD;
    const unsigned short* a0h_row = hh + (size_t)(mt0 * 16 + lr) * DD;
    const unsigned short* a0l_row = hl + (size_t)(mt0 * 16 + lr) * DD;
    const unsigned short* a1h_row = a0h_row + 16 * DD;
    const unsigned short* a1l_row = a0l_row + 16 * DD;

    f32x4 acc0 = {0.f, 0.f, 0.f, 0.f};
    f32x4 acc1 = {0.f, 0.f, 0.f, 0.f};

#pragma unroll 4
    for (int ks = 0; ks < 16; ++ks) {
        const int kb = ks * 32 + kg * 8;
        short8 bh = *(const short8*)(wh_row + kb);
        short8 bl = *(const short8*)(wl_row + kb);
        short8 a0h = *(const short8*)(a0h_row + kb);
        short8 a0l = *(const short8*)(a0l_row + kb);
        short8 a1h = *(const short8*)(a1h_row + kb);
        short8 a1l = *(const short8*)(a1l_row + kb);
        acc0 = __builtin_amdgcn_mfma_f32_16x16x32_bf16(a0h, bh, acc0, 0, 0, 0);
        acc1 = __builtin_amdgcn_mfma_f32_16x16x32_bf16(a1h, bh, acc1, 0, 0, 0);
        acc0 = __builtin_amdgcn_mfma_f32_16x16x32_bf16(a0l, bh, acc0, 0, 0, 0);
        acc1 = __builtin_amdgcn_mfma_f32_16x16x32_bf16(a1l, bh, acc1, 0, 0, 0);
        acc0 = __builtin_amdgcn_mfma_f32_16x16x32_bf16(a0h, bl, acc0, 0, 0, 0);
        acc1 = __builtin_amdgcn_mfma_f32_16x16x32_bf16(a1h, bl, acc1, 0, 0, 0);
    }

#pragma unroll
    for (int t = 0; t < 2; ++t) {
        f32x4 acc = t ? acc1 : acc0;
        const int mbase = (mt0 + t) * 16 + kg * 4;
#pragma unroll
        for (int r = 0; r < 4; ++r) {
            int m = mbase + r;
            int sel = t ? ms1[r] : ms0[r];
            size_t row = (size_t)(m * LL + sel);
            float* dst = (n < GG) ? (acache + row * GG + n)
                                  : (bcache + row * GG + (n - GG));
            *dst = acc[r];
        }
    }
}

// ---------------------------------------------------------------------------
extern "C" void kernel_launch(void* const* d_in, const int* in_sizes, int n_in, void* d_out,
                              int out_size, void* d_ws, size_t ws_size, hipStream_t stream) {
    const float* inp = (const float*)d_in[0];
    const int* length = (const int*)d_in[1];
    const float* word_W = (const float*)d_in[2];
    const float* word_b = (const float*)d_in[3];
    const float* comp_W = (const float*)d_in[4];
    const float* comp_b = (const float*)d_in[5];
    const float* comp_q = (const float*)d_in[6];
    float* out = (float*)d_out;

    float* ws = (float*)d_ws;
    size_t off = 0;
    float* cbuf = ws + off;   off += (size_t)BB * LL * DD;
    float* acache = ws + off; off += (size_t)BB * LL * GG;
    float* bcache = ws + off; off += (size_t)BB * LL * GG;
    float* hout = ws + off;   off += (size_t)BB * DD;
    float* scores = ws + off; off += 2048;
    int* seq_g = (int*)(ws + off); off += BB * 32;
    int* kp_g = (int*)(ws + off);  off += 64;
    int4* rescPre = (int4*)(ws + off); off += BB * 4;
    int* msel = (int*)(ws + off);  off += 64;
    float* cbp = ws + off;    off += GG;
    unsigned short* Wh = (unsigned short*)(ws + off); off += (size_t)5120 * DD / 2;
    unsigned short* Wl = (unsigned short*)(ws + off); off += (size_t)5120 * DD / 2;
    unsigned short* hh = (unsigned short*)(ws + off); off += (size_t)BB * DD / 2;
    unsigned short* hl = (unsigned short*)(ws + off); off += (size_t)BB * DD / 2;
    unsigned short* Ah = (unsigned short*)(ws + off); off += (size_t)BB * LL * DD / 2;
    unsigned short* Al = (unsigned short*)(ws + off); off += (size_t)BB * LL * DD / 2;
    unsigned short* Ih = (unsigned short*)(ws + off); off += (size_t)BB * LL * DD / 2;
    unsigned short* Il = (unsigned short*)(ws + off); off += (size_t)BB * LL * DD / 2;
    unsigned short* Vh = (unsigned short*)(ws + off); off += (size_t)1024 * DD / 2;
    unsigned short* Vl = (unsigned short*)(ws + off); off += (size_t)1024 * DD / 2;
    (void)ws_size; (void)in_sizes; (void)n_in; (void)out_size;

    // one-time splits / permutations
    splitW_k<<<2560, 256, 0, stream>>>(comp_W, Wh, Wl);
    compbp_k<<<10, 256, 0, stream>>>(comp_b, cbp);
    splitF_k<<<768, 256, 0, stream>>>(inp, Ih, Il);
    splitF_k<<<512, 256, 0, stream>>>(word_W, Vh, Vl);

    // word projection via bf16x3 MFMA: h (bf16 hi/lo) + c (fp32)
    gemm64w_mfma<<<192, 256, 0, stream>>>(Ih, Il, Vh, Vl, word_b, Ah, Al, cbuf);

    // a/b caches (pair-major layout) via LDS-staged bf16x3 MFMA
    gemm_big_mfma<<<480, 256, 0, stream>>>(Ah, Al, Wh, Wl, acache, bcache);

    // initial candidate scores
    scoreall_k<<<dim3(12, 64), 256, 0, stream>>>(acache, bcache, cbuf, cbp, comp_q, scores);

    // 23 merge steps: A (rescore+argmax+merge) then B (bf16x3 MFMA GEMM)
    for (int i = 0; i < NSTEP; ++i) {
        stepA_k<<<BB, 256, 0, stream>>>(i, length, cbuf, acache, bcache, hout, hh, hl,
                                        scores, seq_g, kp_g, rescPre, msel, cbp,
                                        comp_q, out);
        if (i < NSTEP - 1) {
            stepB_mfma<<<NTILES, 256, 0, stream>>>(hh, hl, msel, Wh, Wl, acache, bcache);
        }
    }
}

// Round 11
// 587.131 us; speedup vs baseline: 1.0030x; 1.0030x over previous
//
#include <hip/hip_runtime.h>
#include <math.h>

// Problem constants
#define BB 64
#define LL 24
#define DD 512
#define GG 2560        // 5*H
#define NSTEP 23       // LL-1
#define NTILES 160     // stepB n-tiles: 5120/32

// Cache layout (round-8-verified pair-major): a/b cache column for (gate g,
// dim d) is col(d,g) = (d/2)*10 + g*2 + (d%2). splitW_k permutes W rows.

__device__ __forceinline__ float sigm(float x) { return 1.0f / (1.0f + __expf(-x)); }

// bf16 split helpers (RNE)
__device__ __forceinline__ unsigned short f2bf(float x) {
    unsigned u = __float_as_uint(x);
    unsigned r = (u + 0x7fff + ((u >> 16) & 1)) >> 16;
    return (unsigned short)r;
}
__device__ __forceinline__ float bf2f(unsigned short b) {
    return __uint_as_float(((unsigned)b) << 16);
}

using short8 = __attribute__((ext_vector_type(8))) short;
using f32x4 = __attribute__((ext_vector_type(4))) float;

// fp32x8 -> bf16 hi/lo short8 pair (bit-identical to the old splitF path)
__device__ __forceinline__ void cvt8(const float4 a, const float4 b,
                                     short8& h, short8& l) {
    float v[8] = {a.x, a.y, a.z, a.w, b.x, b.y, b.z, b.w};
#pragma unroll
    for (int j = 0; j < 8; ++j) {
        unsigned short hv = f2bf(v[j]);
        h[j] = (short)hv;
        l[j] = (short)f2bf(v[j] - bf2f(hv));
    }
}

// gate math for one dim pair (round-8 verified)
__device__ __forceinline__ void gatepair(const float* ar, const float* br,
                                         const float* cb,
                                         float cl0, float cl1, float cr0, float cr1,
                                         float nh[2], float nc[2]) {
    float2 A0 = *(const float2*)(ar + 0), B0 = *(const float2*)(br + 0), C0 = *(const float2*)(cb + 0);
    float2 A1 = *(const float2*)(ar + 2), B1 = *(const float2*)(br + 2), C1 = *(const float2*)(cb + 2);
    float2 A2 = *(const float2*)(ar + 4), B2 = *(const float2*)(br + 4), C2 = *(const float2*)(cb + 4);
    float2 A3 = *(const float2*)(ar + 6), B3 = *(const float2*)(br + 6), C3 = *(const float2*)(cb + 6);
    float2 A4 = *(const float2*)(ar + 8), B4 = *(const float2*)(br + 8), C4 = *(const float2*)(cb + 8);
    float gi0 = A0.x + B0.x + C0.x, gi1 = A0.y + B0.y + C0.y;
    float gfl0 = A1.x + B1.x + C1.x, gfl1 = A1.y + B1.y + C1.y;
    float gfr0 = A2.x + B2.x + C2.x, gfr1 = A2.y + B2.y + C2.y;
    float gu0 = A3.x + B3.x + C3.x, gu1 = A3.y + B3.y + C3.y;
    float go0 = A4.x + B4.x + C4.x, go1 = A4.y + B4.y + C4.y;
    nc[0] = cl0 * sigm(gfl0 + 1.f) + cr0 * sigm(gfr0 + 1.f) + tanhf(gu0) * sigm(gi0);
    nc[1] = cl1 * sigm(gfl1 + 1.f) + cr1 * sigm(gfr1 + 1.f) + tanhf(gu1) * sigm(gi1);
    nh[0] = sigm(go0) * tanhf(nc[0]);
    nh[1] = sigm(go1) * tanhf(nc[1]);
}

// ---------------------------------------------------------------------------
// one-time: split comp_W into bf16 hi/lo, PERMUTED rows [5120][512]; also
// produces the permuted bias cbp (folded in: blocks 0..9 -> one less launch).
// ---------------------------------------------------------------------------
__global__ __launch_bounds__(256) void splitW_k(const float* __restrict__ comp_W,
                                                unsigned short* __restrict__ Wh,
                                                unsigned short* __restrict__ Wl,
                                                const float* __restrict__ comp_b,
                                                float* __restrict__ cbp) {
    if (blockIdx.x < 10) {
        int c = blockIdx.x * 256 + threadIdx.x;   // 2560
        int gg = (c % 10) >> 1;
        int dd = (c / 10) * 2 + (c & 1);
        cbp[c] = comp_b[gg * 512 + dd];
    }
    int t = (blockIdx.x * 256 + threadIdx.x) * 4;
    int n = t >> 9;
    int k = t & 511;
    int p = (n >= GG) ? 1 : 0;
    int r = n - p * GG;
    int g = (r % 10) >> 1;
    int d = (r / 10) * 2 + (r & 1);
    const float* src = comp_W + (size_t)(g * 512 + d) * (2 * DD) + p * DD + k;
    float4 v = *(const float4*)src;
    ushort4 h, l;
    h.x = f2bf(v.x); l.x = f2bf(v.x - bf2f(h.x));
    h.y = f2bf(v.y); l.y = f2bf(v.y - bf2f(h.y));
    h.z = f2bf(v.z); l.z = f2bf(v.z - bf2f(h.z));
    h.w = f2bf(v.w); l.w = f2bf(v.w - bf2f(h.w));
    *(ushort4*)(Wh + t) = h;
    *(ushort4*)(Wl + t) = l;
}

// ---------------------------------------------------------------------------
// gemm64w_mfma v2: word projection via bf16x3 MFMA, reading fp32 inp/word_W
// directly (bf16 hi/lo split fused into the staging -> no splitF launches).
// M=1536, N=1024, K=512; 192 blocks (64m x 128n), 4 waves 2x2, BK=64.
// Epilogue: n<512 -> h as bf16 hi/lo (Ah/Al); n>=512 -> c as fp32 (O1).
// ---------------------------------------------------------------------------
__global__ __launch_bounds__(256) void gemm64w_mfma(
    const float* __restrict__ inp, const float* __restrict__ wordW,
    const float* __restrict__ bias,
    unsigned short* __restrict__ Ah, unsigned short* __restrict__ Al,
    float* __restrict__ O1) {
    __shared__ unsigned short AhS[64][72];
    __shared__ unsigned short AlS[64][72];
    __shared__ unsigned short BhS[128][72];
    __shared__ unsigned short BlS[128][72];

    const int tid = threadIdx.x;
    const int m0 = (blockIdx.x % 24) * 64;
    const int n0 = (blockIdx.x / 24) * 128;

    const int w = tid >> 6, lane = tid & 63;
    const int mq = w >> 1, nq = w & 1;
    const int lr = lane & 15, kg = lane >> 4;

    const int srow = tid >> 3;   // 0..31 (+it*32)
    const int sk8 = tid & 7;

    const float* agf = inp + (size_t)(m0 + srow) * DD + sk8 * 8;
    const float* bgf = wordW + (size_t)(n0 + srow) * DD + sk8 * 8;

    f32x4 acc[2][4];
#pragma unroll
    for (int mt = 0; mt < 2; ++mt)
#pragma unroll
        for (int nt = 0; nt < 4; ++nt) acc[mt][nt] = (f32x4){0.f, 0.f, 0.f, 0.f};

    float4 rA[2][2], rB[4][2];

#define LOADT(kt)                                                            \
    {                                                                        \
        _Pragma("unroll")                                                    \
        for (int it = 0; it < 2; ++it) {                                     \
            const size_t ro = (size_t)it * 32 * DD + (kt);                   \
            rA[it][0] = *(const float4*)(agf + ro);                          \
            rA[it][1] = *(const float4*)(agf + ro + 4);                      \
        }                                                                    \
        _Pragma("unroll")                                                    \
        for (int it = 0; it < 4; ++it) {                                     \
            const size_t ro = (size_t)it * 32 * DD + (kt);                   \
            rB[it][0] = *(const float4*)(bgf + ro);                          \
            rB[it][1] = *(const float4*)(bgf + ro + 4);                      \
        }                                                                    \
    }
#define WRITET()                                                             \
    {                                                                        \
        _Pragma("unroll")                                                    \
        for (int it = 0; it < 2; ++it) {                                     \
            const int row = srow + it * 32;                                  \
            short8 h8, l8;                                                   \
            cvt8(rA[it][0], rA[it][1], h8, l8);                              \
            *(short8*)&AhS[row][sk8 * 8] = h8;                               \
            *(short8*)&AlS[row][sk8 * 8] = l8;                               \
        }                                                                    \
        _Pragma("unroll")                                                    \
        for (int it = 0; it < 4; ++it) {                                     \
            const int row = srow + it * 32;                                  \
            short8 h8, l8;                                                   \
            cvt8(rB[it][0], rB[it][1], h8, l8);                              \
            *(short8*)&BhS[row][sk8 * 8] = h8;                               \
            *(short8*)&BlS[row][sk8 * 8] = l8;                               \
        }                                                                    \
    }

    LOADT(0);
    WRITET();
    __syncthreads();

    for (int kti = 0; kti < 8; ++kti) {
        if (kti + 1 < 8) LOADT((kti + 1) * 64);
#pragma unroll
        for (int ks2 = 0; ks2 < 2; ++ks2) {
            const int kb = ks2 * 32 + kg * 8;
            short8 fah[2], fal[2], fbh[4], fbl[4];
#pragma unroll
            for (int t = 0; t < 2; ++t) {
                fah[t] = *(const short8*)&AhS[mq * 32 + t * 16 + lr][kb];
                fal[t] = *(const short8*)&AlS[mq * 32 + t * 16 + lr][kb];
            }
#pragma unroll
            for (int t = 0; t < 4; ++t) {
                fbh[t] = *(const short8*)&BhS[nq * 64 + t * 16 + lr][kb];
                fbl[t] = *(const short8*)&BlS[nq * 64 + t * 16 + lr][kb];
            }
#pragma unroll
            for (int mt = 0; mt < 2; ++mt)
#pragma unroll
                for (int nt = 0; nt < 4; ++nt) {
                    acc[mt][nt] = __builtin_amdgcn_mfma_f32_16x16x32_bf16(fal[mt], fbh[nt], acc[mt][nt], 0, 0, 0);
                    acc[mt][nt] = __builtin_amdgcn_mfma_f32_16x16x32_bf16(fah[mt], fbl[nt], acc[mt][nt], 0, 0, 0);
                    acc[mt][nt] = __builtin_amdgcn_mfma_f32_16x16x32_bf16(fah[mt], fbh[nt], acc[mt][nt], 0, 0, 0);
                }
        }
        __syncthreads();
        if (kti + 1 < 8) {
            WRITET();
            __syncthreads();
        }
    }
#undef LOADT
#undef WRITET

#pragma unroll
    for (int mt = 0; mt < 2; ++mt) {
        const int mbase = m0 + mq * 32 + mt * 16 + kg * 4;
#pragma unroll
        for (int nt = 0; nt < 4; ++nt) {
            const int n = n0 + nq * 64 + nt * 16 + lr;
            const float bv = bias[n];
#pragma unroll
            for (int r = 0; r < 4; ++r) {
                const int m = mbase + r;
                float v = acc[mt][nt][r] + bv;
                if (n < DD) {
                    unsigned short hv = f2bf(v);
                    Ah[(size_t)m * DD + n] = hv;
                    Al[(size_t)m * DD + n] = f2bf(v - bf2f(hv));
                } else {
                    O1[(size_t)m * DD + (n - DD)] = v;
                }
            }
        }
    }
}

// ---------------------------------------------------------------------------
// gemm_big_mfma v3: LDS-staged bf16x3 MFMA GEMM (round-6 verified, unchanged)
// ---------------------------------------------------------------------------
__global__ __launch_bounds__(256) void gemm_big_mfma(
    const unsigned short* __restrict__ Ah, const unsigned short* __restrict__ Al,
    const unsigned short* __restrict__ Wh, const unsigned short* __restrict__ Wl,
    float* __restrict__ O0, float* __restrict__ O1) {
    __shared__ unsigned short AhS[128][72];
    __shared__ unsigned short AlS[128][72];
    __shared__ unsigned short BhS[128][72];
    __shared__ unsigned short BlS[128][72];

    const int tid = threadIdx.x;
    const int xcd = blockIdx.x & 7, idx = blockIdx.x >> 3;
    const int n0 = (xcd * 5 + idx % 5) * 128;
    const int m0 = (idx / 5) * 128;

    const int w = tid >> 6, lane = tid & 63;
    const int mq = w >> 1, nq = w & 1;
    const int lr = lane & 15, kg = lane >> 4;

    const int srow = tid >> 3;
    const int sk8 = tid & 7;

    const unsigned short* agh = Ah + (size_t)(m0 + srow) * DD + sk8 * 8;
    const unsigned short* agl = Al + (size_t)(m0 + srow) * DD + sk8 * 8;
    const unsigned short* bgh = Wh + (size_t)(n0 + srow) * DD + sk8 * 8;
    const unsigned short* bgl = Wl + (size_t)(n0 + srow) * DD + sk8 * 8;

    f32x4 acc[4][4];
#pragma unroll
    for (int mt = 0; mt < 4; ++mt)
#pragma unroll
        for (int nt = 0; nt < 4; ++nt) acc[mt][nt] = (f32x4){0.f, 0.f, 0.f, 0.f};

    short8 rAh[4], rAl[4], rBh[4], rBl[4];

#define LOADT(kt)                                                            \
    {                                                                        \
        _Pragma("unroll")                                                    \
        for (int it = 0; it < 4; ++it) {                                     \
            const size_t ro = (size_t)it * 32 * DD + (kt);                   \
            rAh[it] = *(const short8*)(agh + ro);                            \
            rAl[it] = *(const short8*)(agl + ro);                            \
            rBh[it] = *(const short8*)(bgh + ro);                            \
            rBl[it] = *(const short8*)(bgl + ro);                            \
        }                                                                    \
    }
#define WRITET()                                                             \
    {                                                                        \
        _Pragma("unroll")                                                    \
        for (int it = 0; it < 4; ++it) {                                     \
            const int row = srow + it * 32;                                  \
            *(short8*)&AhS[row][sk8 * 8] = rAh[it];                          \
            *(short8*)&AlS[row][sk8 * 8] = rAl[it];                          \
            *(short8*)&BhS[row][sk8 * 8] = rBh[it];                          \
            *(short8*)&BlS[row][sk8 * 8] = rBl[it];                          \
        }                                                                    \
    }

    LOADT(0);
    WRITET();
    __syncthreads();

    for (int kti = 0; kti < 8; ++kti) {
        if (kti + 1 < 8) LOADT((kti + 1) * 64);
#pragma unroll
        for (int ks2 = 0; ks2 < 2; ++ks2) {
            const int kb = ks2 * 32 + kg * 8;
            short8 fah[4], fal[4], fbh[4], fbl[4];
#pragma unroll
            for (int t = 0; t < 4; ++t) {
                fah[t] = *(const short8*)&AhS[mq * 64 + t * 16 + lr][kb];
                fal[t] = *(const short8*)&AlS[mq * 64 + t * 16 + lr][kb];
                fbh[t] = *(const short8*)&BhS[nq * 64 + t * 16 + lr][kb];
                fbl[t] = *(const short8*)&BlS[nq * 64 + t * 16 + lr][kb];
            }
#pragma unroll
            for (int mt = 0; mt < 4; ++mt)
#pragma unroll
                for (int nt = 0; nt < 4; ++nt) {
                    acc[mt][nt] = __builtin_amdgcn_mfma_f32_16x16x32_bf16(fal[mt], fbh[nt], acc[mt][nt], 0, 0, 0);
                    acc[mt][nt] = __builtin_amdgcn_mfma_f32_16x16x32_bf16(fah[mt], fbl[nt], acc[mt][nt], 0, 0, 0);
                    acc[mt][nt] = __builtin_amdgcn_mfma_f32_16x16x32_bf16(fah[mt], fbh[nt], acc[mt][nt], 0, 0, 0);
                }
        }
        __syncthreads();
        if (kti + 1 < 8) {
            WRITET();
            __syncthreads();
        }
    }
#undef LOADT
#undef WRITET

#pragma unroll
    for (int mt = 0; mt < 4; ++mt) {
        const int mbase = m0 + mq * 64 + mt * 16 + kg * 4;
#pragma unroll
        for (int nt = 0; nt < 4; ++nt) {
            const int n = n0 + nq * 64 + nt * 16 + lr;
#pragma unroll
            for (int r = 0; r < 4; ++r) {
                const int m = mbase + r;
                float* dst = (n < GG) ? (O0 + (size_t)m * GG + n)
                                      : (O1 + (size_t)m * GG + (n - GG));
                *dst = acc[mt][nt][r];
            }
        }
    }
}

// ---------------------------------------------------------------------------
// half-block (128-lane) candidate scorer — pair layout (round-8 verified)
// ---------------------------------------------------------------------------
__device__ __forceinline__ float half_dot(const float* __restrict__ ar,
                                          const float* __restrict__ br,
                                          const float* __restrict__ cbp,
                                          const float* __restrict__ cl,
                                          const float* __restrict__ cr,
                                          const float* __restrict__ q, int lane) {
    float part = 0.f;
#pragma unroll
    for (int pr = lane; pr < 256; pr += 128) {
        const int base = pr * 10, d0 = pr * 2;
        float nh[2], nc[2];
        gatepair(ar + base, br + base, cbp + base,
                 cl[d0], cl[d0 + 1], cr[d0], cr[d0 + 1], nh, nc);
        float2 Q = *(const float2*)(q + d0);
        part += nh[0] * Q.x + nh[1] * Q.y;
    }
#pragma unroll
    for (int off = 32; off; off >>= 1) part += __shfl_down(part, off);
    return part;
}

// ---------------------------------------------------------------------------
// initial scores: grid (12, 64)
// ---------------------------------------------------------------------------
__global__ __launch_bounds__(256) void scoreall_k(const float* __restrict__ acache,
                                                  const float* __restrict__ bcache,
                                                  const float* __restrict__ cbuf,
                                                  const float* __restrict__ cbp,
                                                  const float* __restrict__ q,
                                                  float* __restrict__ scores_g) {
    __shared__ float red_s[4];
    const int tid = threadIdx.x;
    const int b = blockIdx.y;
    const int p = blockIdx.x * 2 + (tid >> 7);
    const bool valid = p < NSTEP;
    float w = 0.f;
    if (valid) {
        w = half_dot(acache + (size_t)(b * LL + p) * GG,
                     bcache + (size_t)(b * LL + p + 1) * GG, cbp,
                     cbuf + (size_t)(b * LL + p) * DD,
                     cbuf + (size_t)(b * LL + p + 1) * DD, q, tid & 127);
    }
    if ((tid & 63) == 0) red_s[tid >> 6] = w;
    __syncthreads();
    if ((tid == 0 || tid == 128) && valid) {
        int base = tid >> 6;
        scores_g[b * NSTEP + p] = red_s[base] + red_s[base + 1];
    }
}

// ---------------------------------------------------------------------------
// stepA (round-10 verified, unchanged): rescPre early rescore, wave argmax,
// merge, state shift.
// ---------------------------------------------------------------------------
__global__ __launch_bounds__(256) void stepA_k(
    int i, const int* __restrict__ length, float* __restrict__ cbuf,
    const float* __restrict__ acache, const float* __restrict__ bcache,
    float* __restrict__ hout, unsigned short* __restrict__ hh,
    unsigned short* __restrict__ hl, float* __restrict__ scores_g,
    int* __restrict__ seq_g, int* __restrict__ kp_g, int4* __restrict__ rescPre,
    int* __restrict__ msel, const float* __restrict__ cbp,
    const float* __restrict__ q, float* __restrict__ out) {
    __shared__ float red_s[4];
    __shared__ float sc_l[32];
    __shared__ int seq_l[32];
    __shared__ int k_sh;
    const int tid = threadIdx.x;
    const int b = blockIdx.x;
    const int lenb = length[b];
    const int ncand = NSTEP - i;

    // rescore first: row ids come from rescPre (no seq dependency)
    if (i > 0) {
        const int4 rp = rescPre[b];           // {sL, sN, sN or -1, sR}
        const int sl = (tid < 128) ? rp.x : rp.z;
        const int sr = (tid < 128) ? rp.y : rp.w;
        float w = 0.f;
        if (sl >= 0) {
            w = half_dot(acache + (size_t)(b * LL + sl) * GG,
                         bcache + (size_t)(b * LL + sr) * GG, cbp,
                         cbuf + (size_t)(b * LL + sl) * DD,
                         cbuf + (size_t)(b * LL + sr) * DD, q, tid & 127);
        }
        if ((tid & 63) == 0) red_s[tid >> 6] = w;
    }

    // state staging (overlaps the rescore loads above)
    if (i == 0) {
        if (tid < LL) seq_l[tid] = tid;
    } else {
        if (tid < LL - i) seq_l[tid] = seq_g[b * 32 + tid];
    }
    if (tid < ncand) sc_l[tid] = scores_g[b * NSTEP + tid];
    __syncthreads();

    if (i > 0 && tid == 0) {
        const int4 rp = rescPre[b];
        const int kp = kp_g[b];
        if (rp.x >= 0) sc_l[kp - 1] = red_s[0] + red_s[1];
        if (rp.z >= 0) sc_l[kp] = red_s[2] + red_s[3];
    }
    __syncthreads();

    if (i + 1 < lenb) {
        // wave-parallel argmax over sc_l[0..vmax] (first-index tie-break)
        if (tid < 64) {
            const int vmax = lenb - i - 2;
            float v = (tid <= vmax) ? sc_l[tid] : -3.0e38f;
            int idx = tid;
#pragma unroll
            for (int off = 32; off; off >>= 1) {
                float v2 = __shfl_down(v, off);
                int i2 = __shfl_down(idx, off);
                if (v2 > v || (v2 == v && i2 < idx)) { v = v2; idx = i2; }
            }
            if (tid == 0) k_sh = idx;
        }
        __syncthreads();
        const int k = k_sh;
        const int sl = seq_l[k], sr = seq_l[k + 1];
        // capture next step's rescore pair item-ids PRE-shift
        int sLn = -1, sRn = -1;
        if (tid == 0) {
            if (k > 0) sLn = seq_l[k - 1];
            if (k < NSTEP - i - 1) sRn = seq_l[k + 2];
        }
        const float* ar = acache + (size_t)(b * LL + sl) * GG;
        const float* br = bcache + (size_t)(b * LL + sr) * GG;
        const float* cl = cbuf + (size_t)(b * LL + sl) * DD;
        const float* cr = cbuf + (size_t)(b * LL + sr) * DD;
        {
            const int d = 2 * tid, base = tid * 10;
            float nh[2], nc[2];
            gatepair(ar + base, br + base, cbp + base,
                     cl[d], cl[d + 1], cr[d], cr[d + 1], nh, nc);
            *(float2*)(cbuf + (size_t)(b * LL + sl) * DD + d) = make_float2(nc[0], nc[1]);
            *(float2*)(hout + (size_t)b * DD + d) = make_float2(nh[0], nh[1]);
            ushort2 hv, lv;
            hv.x = f2bf(nh[0]); lv.x = f2bf(nh[0] - bf2f(hv.x));
            hv.y = f2bf(nh[1]); lv.y = f2bf(nh[1] - bf2f(hv.y));
            *(ushort2*)(hh + (size_t)b * DD + d) = hv;
            *(ushort2*)(hl + (size_t)b * DD + d) = lv;
            if (i == NSTEP - 1)
                *(float2*)(out + (size_t)b * DD + d) = make_float2(nh[0], nh[1]);
        }
        float sv = (tid + 1 < ncand) ? sc_l[tid + 1] : 0.f;
        int qv = (tid + 1 < LL - i) ? seq_l[tid + 1] : 0;
        __syncthreads();
        if (tid >= k + 1 && tid <= ncand - 2) sc_l[tid] = sv;
        if (tid >= k + 1 && tid <= LL - i - 2) seq_l[tid] = qv;
        if (tid < ncand - 1) scores_g[b * NSTEP + tid] = sc_l[tid];
        if (tid < LL - i - 1) seq_g[b * 32 + tid] = seq_l[tid];
        if (tid == 0) {
            kp_g[b] = k;
            msel[b] = sl;
            rescPre[b] = make_int4(sLn, sl, (sRn >= 0) ? sl : -1, sRn);
        }
    } else {
        if (tid == 0) rescPre[b] = make_int4(-1, 0, -1, 0);
        if (i == NSTEP - 1) {
            const int d = 2 * tid;
            *(float2*)(out + (size_t)b * DD + d) = *(const float2*)(hout + (size_t)b * DD + d);
        }
    }
}

// ---------------------------------------------------------------------------
// stepB (round-10 verified, unchanged): barrier-free, per-thread msel regs.
// ---------------------------------------------------------------------------
__global__ __launch_bounds__(256) void stepB_mfma(
    const unsigned short* __restrict__ hh, const unsigned short* __restrict__ hl,
    const int* __restrict__ msel,
    const unsigned short* __restrict__ Wh, const unsigned short* __restrict__ Wl,
    float* __restrict__ acache, float* __restrict__ bcache) {
    const int tid = threadIdx.x;
    const int bid = blockIdx.x;
    const int w = tid >> 6, lane = tid & 63;
    const int mt0 = (w >> 1) * 2;
    const int nt = w & 1;
    const int lr = lane & 15;
    const int kg = lane >> 4;
    const int n = bid * 32 + nt * 16 + lr;

    int ms0[4], ms1[4];
#pragma unroll
    for (int r = 0; r < 4; ++r) {
        ms0[r] = msel[mt0 * 16 + kg * 4 + r];
        ms1[r] = msel[(mt0 + 1) * 16 + kg * 4 + r];
    }

    const unsigned short* wh_row = Wh + (size_t)n * DD;
    const unsigned short* wl_row = Wl + (size_t)n * DD;
    const unsigned short* a0h_row = hh + (size_t)(mt0 * 16 + lr) * DD;
    const unsigned short* a0l_row = hl + (size_t)(mt0 * 16 + lr) * DD;
    const unsigned short* a1h_row = a0h_row + 16 * DD;
    const unsigned short* a1l_row = a0l_row + 16 * DD;

    f32x4 acc0 = {0.f, 0.f, 0.f, 0.f};
    f32x4 acc1 = {0.f, 0.f, 0.f, 0.f};

#pragma unroll 4
    for (int ks = 0; ks < 16; ++ks) {
        const int kb = ks * 32 + kg * 8;
        short8 bh = *(const short8*)(wh_row + kb);
        short8 bl = *(const short8*)(wl_row + kb);
        short8 a0h = *(const short8*)(a0h_row + kb);
        short8 a0l = *(const short8*)(a0l_row + kb);
        short8 a1h = *(const short8*)(a1h_row + kb);
        short8 a1l = *(const short8*)(a1l_row + kb);
        acc0 = __builtin_amdgcn_mfma_f32_16x16x32_bf16(a0h, bh, acc0, 0, 0, 0);
        acc1 = __builtin_amdgcn_mfma_f32_16x16x32_bf16(a1h, bh, acc1, 0, 0, 0);
        acc0 = __builtin_amdgcn_mfma_f32_16x16x32_bf16(a0l, bh, acc0, 0, 0, 0);
        acc1 = __builtin_amdgcn_mfma_f32_16x16x32_bf16(a1l, bh, acc1, 0, 0, 0);
        acc0 = __builtin_amdgcn_mfma_f32_16x16x32_bf16(a0h, bl, acc0, 0, 0, 0);
        acc1 = __builtin_amdgcn_mfma_f32_16x16x32_bf16(a1h, bl, acc1, 0, 0, 0);
    }

#pragma unroll
    for (int t = 0; t < 2; ++t) {
        f32x4 acc = t ? acc1 : acc0;
        const int mbase = (mt0 + t) * 16 + kg * 4;
#pragma unroll
        for (int r = 0; r < 4; ++r) {
            int m = mbase + r;
            int sel = t ? ms1[r] : ms0[r];
            size_t row = (size_t)(m * LL + sel);
            float* dst = (n < GG) ? (acache + row * GG + n)
                                  : (bcache + row * GG + (n - GG));
            *dst = acc[r];
        }
    }
}

// ---------------------------------------------------------------------------
extern "C" void kernel_launch(void* const* d_in, const int* in_sizes, int n_in, void* d_out,
                              int out_size, void* d_ws, size_t ws_size, hipStream_t stream) {
    const float* inp = (const float*)d_in[0];
    const int* length = (const int*)d_in[1];
    const float* word_W = (const float*)d_in[2];
    const float* word_b = (const float*)d_in[3];
    const float* comp_W = (const float*)d_in[4];
    const float* comp_b = (const float*)d_in[5];
    const float* comp_q = (const float*)d_in[6];
    float* out = (float*)d_out;

    float* ws = (float*)d_ws;
    size_t off = 0;
    float* cbuf = ws + off;   off += (size_t)BB * LL * DD;
    float* acache = ws + off; off += (size_t)BB * LL * GG;
    float* bcache = ws + off; off += (size_t)BB * LL * GG;
    float* hout = ws + off;   off += (size_t)BB * DD;
    float* scores = ws + off; off += 2048;
    int* seq_g = (int*)(ws + off); off += BB * 32;
    int* kp_g = (int*)(ws + off);  off += 64;
    int4* rescPre = (int4*)(ws + off); off += BB * 4;
    int* msel = (int*)(ws + off);  off += 64;
    float* cbp = ws + off;    off += GG;
    unsigned short* Wh = (unsigned short*)(ws + off); off += (size_t)5120 * DD / 2;
    unsigned short* Wl = (unsigned short*)(ws + off); off += (size_t)5120 * DD / 2;
    unsigned short* hh = (unsigned short*)(ws + off); off += (size_t)BB * DD / 2;
    unsigned short* hl = (unsigned short*)(ws + off); off += (size_t)BB * DD / 2;
    unsigned short* Ah = (unsigned short*)(ws + off); off += (size_t)BB * LL * DD / 2;
    unsigned short* Al = (unsigned short*)(ws + off); off += (size_t)BB * LL * DD / 2;
    (void)ws_size; (void)in_sizes; (void)n_in; (void)out_size;

    // one-time: W split+permute (+ folded cbp permutation)
    splitW_k<<<2560, 256, 0, stream>>>(comp_W, Wh, Wl, comp_b, cbp);

    // word projection via bf16x3 MFMA, fp32 inputs, fused hi/lo staging split
    gemm64w_mfma<<<192, 256, 0, stream>>>(inp, word_W, word_b, Ah, Al, cbuf);

    // a/b caches (pair-major layout) via LDS-staged bf16x3 MFMA
    gemm_big_mfma<<<480, 256, 0, stream>>>(Ah, Al, Wh, Wl, acache, bcache);

    // initial candidate scores
    scoreall_k<<<dim3(12, 64), 256, 0, stream>>>(acache, bcache, cbuf, cbp, comp_q, scores);

    // 23 merge steps: A (rescore+argmax+merge) then B (bf16x3 MFMA GEMM)
    for (int i = 0; i < NSTEP; ++i) {
        stepA_k<<<BB, 256, 0, stream>>>(i, length, cbuf, acache, bcache, hout, hh, hl,
                                        scores, seq_g, kp_g, rescPre, msel, cbp,
                                        comp_q, out);
        if (i < NSTEP - 1) {
            stepB_mfma<<<NTILES, 256, 0, stream>>>(hh, hl, msel, Wh, Wl, acache, bcache);
        }
    }
}